// Round 22
// baseline (118.602 us; speedup 1.0000x reference)
//
#include <hip/hip_runtime.h>
#include <hip/hip_bf16.h>

// Conv2d 3x3 s1 p1, NCHW/OIHW fp32 -> fp32. bf16 implicit GEMM.
// R21 = R11 conv structure (best: 12 phases, 12-slot ring, W L2->VGPR
// s-slice prefetch) + FUSED input transpose: conv stages NCHW fp32
// directly (predicated loads at phase top, f2bf + ds_write at phase end).
// prep_input kernel eliminated; ws holds only weights.

#define C_IN   128
#define K_OUT  256
#define HW     56
#define IMG    3136
#define NBATCH 32
#define PW     58
#define WT_WS_USHORT ((size_t)12*2*1536*8)           // [p][koh][1536ch][8]

typedef __bf16 bf16x8 __attribute__((ext_vector_type(8)));
typedef float  f32x4  __attribute__((ext_vector_type(4)));
typedef unsigned short ushort8 __attribute__((ext_vector_type(8)));

__device__ inline unsigned short f2bf(float f) {
    unsigned int u = __builtin_bit_cast(unsigned int, f);
    u += ((u >> 16) & 1u) + 0x7FFFu;   // RNE
    return (unsigned short)(u >> 16);
}

// ---- prep B: OIHW fp32 -> [p=cq*3+r][koh:2][s:3][koq:8][cc:4][kor:16][8c] ----
__global__ void prep_weights(const float* __restrict__ w,
                             unsigned short* __restrict__ dst) {
    int chunk = blockIdx.x * 256 + threadIdx.x;  // 36864 chunks
    int p = chunk / 3072, rem = chunk - p * 3072;
    int koh = rem / 1536, rem2 = rem - koh * 1536;
    int s = rem2 / 512, rem3 = rem2 - s * 512;
    int koq = rem3 >> 6, cc = (rem3 >> 4) & 3, kor = rem3 & 15;
    int ko = koh * 128 + koq * 16 + kor;
    int cq = p / 3, r = p - 3 * cq;
    ushort8 v;
#pragma unroll
    for (int e = 0; e < 8; ++e)
        v[e] = f2bf(w[(ko * C_IN + cq * 32 + cc * 8 + e) * 9 + r * 3 + s]);
    ((ushort8*)dst)[chunk] = v;
}

// ---- main conv ----
// Block 256 thr = 4 waves (2ko x 2px), 128ko x 224px (4 output rows).
// LDS: 12-slot input row ring, 4KB/slot, slot(c,t) = (6c+t) % 12, layout
// per row [Xq:4][cc:4][Xr:16][8c] (X = padded x, 0..57 stored in 0..63).
// Input staged IN-KERNEL from NCHW fp32: loads at phase top, f2bf +
// ds_write_b128 at phase end (latency hidden under 3 MFMA steps).
// Weights: per-wave A s-slices from L2 into wbuf[2][4] (2-deep).
__global__ __launch_bounds__(256, 2) void conv_mfma(
        const float* __restrict__ inp,
        const unsigned short* __restrict__ Wt,
        const float* __restrict__ bias,
        float* __restrict__ out) {
    __shared__ unsigned short smem[24576];       // 48 KB ring

    const int tid = threadIdx.x;
    const int lane = tid & 63, wv = tid >> 6;
    const int l15 = lane & 15, lk = lane >> 4;
    const int koh = blockIdx.y;
    const int by = blockIdx.x;
    const int n = by / 14, rb = (by % 14) * 4;

    const int wkol = (wv & 1) * 64;                // wave ko base (in block)
    const int wpx  = (wv >> 1) * 112;              // wave px base (local)
    const int wlane = (wv & 1) * 2048 + lk * 128 + l15 * 8;   // W ushort off

    // staging decode (fixed per thread): chunk tid = [Xq][cc][Xr]
    const int Xq_ = tid >> 6, cc_ = (tid >> 4) & 3, Xr_ = tid & 15;
    const int X_ = Xq_ * 16 + Xr_;
    const bool xok = (X_ >= 1) & (X_ <= 56);
    const int xi = xok ? X_ - 1 : 0;
    const float* ibase = inp + ((size_t)(n * C_IN + cc_ * 8)) * IMG + xi;

    int yl[7], xp[3][7];
#pragma unroll
    for (int nf = 0; nf < 7; ++nf) {
        int p = wpx + nf * 16 + l15;               // local pixel 0..223
        yl[nf] = p / 56;
        int x = p - yl[nf] * 56;
#pragma unroll
        for (int s = 0; s < 3; ++s) {
            int X = x + s;
            xp[s][nf] = ((X >> 4) << 10) + lk * 256 + ((X & 15) << 4);
        }
    }

    f32x4 acc[4][7];
#pragma unroll
    for (int m = 0; m < 4; ++m)
#pragma unroll
        for (int nf = 0; nf < 7; ++nf) acc[m][nf] = (f32x4)0.0f;

    bf16x8 wbuf[2][4];

// load W slice G_ (panel G_/3, s = G_%3) into wbuf[G_&1]
#define LOAD_WS(G_) do {                                                    \
    if constexpr ((G_) <= 35) {                                             \
        constexpr int p_ = (G_) / 3, sx_ = (G_) % 3;                        \
        const unsigned short* wp = Wt + ((size_t)(p_ * 2 + koh)) * 12288    \
                                   + sx_ * 4096 + wlane;                    \
        _Pragma("unroll")                                                   \
        for (int m = 0; m < 4; ++m)                                         \
            wbuf[(G_) & 1][m] = *(const bf16x8*)(wp + m * 512);             \
    } } while (0)

// issue 8 predicated fp32 loads for row rb+T_ of c-quarter C_ into D_
#define ILOAD(C_, T_, D_) do {                                              \
    int py_ = rb + (T_);                                                    \
    bool ok_ = xok & (py_ >= 1) & (py_ <= 56);                              \
    const float* bp_ = ibase + (size_t)(C_) * 32 * IMG + (py_ - 1) * 56;    \
    _Pragma("unroll")                                                       \
    for (int e = 0; e < 8; ++e) D_[e] = ok_ ? bp_[e * IMG] : 0.0f;          \
} while (0)

// convert + write row chunk to ring slot (6C_+T_)%12
#define IWRITE(C_, T_, D_) do {                                             \
    ushort8 v_;                                                             \
    _Pragma("unroll")                                                       \
    for (int e = 0; e < 8; ++e) v_[e] = f2bf(D_[e]);                        \
    *(ushort8*)&smem[(((6 * (C_) + (T_)) % 12) * 2048) + tid * 8] = v_;     \
} while (0)

#define STEP(PH, S_) do {                                                   \
    constexpr int g_ = (PH) * 3 + (S_);                                     \
    LOAD_WS(g_ + 1);                                                        \
    { const char* ib = (const char*)smem;                                   \
      bf16x8 b[7];                                                          \
      _Pragma("unroll")                                                     \
      for (int nf = 0; nf < 7; ++nf)                                        \
          b[nf] = *(const bf16x8*)(ib + roff[nf] + xp[(S_)][nf]);           \
      __builtin_amdgcn_s_setprio(1);                                        \
      _Pragma("unroll")                                                     \
      for (int m = 0; m < 4; ++m)                                           \
          _Pragma("unroll")                                                 \
          for (int nf = 0; nf < 7; ++nf)                                    \
              acc[m][nf] = __builtin_amdgcn_mfma_f32_16x16x32_bf16(         \
                  wbuf[g_ & 1][m], b[nf], acc[m][nf], 0, 0, 0);             \
      __builtin_amdgcn_s_setprio(0);                                        \
    }                                                                       \
} while (0)

    // prologue: stage rows (0,0..3) through registers, then W slice 0
    {
        float p0[8], p1[8], p2[8], p3[8];
        ILOAD(0, 0, p0); ILOAD(0, 1, p1); ILOAD(0, 2, p2); ILOAD(0, 3, p3);
        IWRITE(0, 0, p0); IWRITE(0, 1, p1); IWRITE(0, 2, p2); IWRITE(0, 3, p3);
    }
    LOAD_WS(0);
    asm volatile("s_waitcnt lgkmcnt(0)" ::: "memory");
    asm volatile("s_barrier" ::: "memory");

#define PHASE(PH) do {                                                      \
    constexpr int cqp_ = (PH) / 3, rp_ = (PH) % 3;                          \
    float s0[8], s1[8];                                                     \
    if constexpr (rp_ == 0) {                                               \
        ILOAD(cqp_, 4, s0);                                                 \
        if constexpr (cqp_ < 3) ILOAD(cqp_ + 1, 0, s1);                     \
    } else if constexpr (rp_ == 1) {                                        \
        ILOAD(cqp_, 5, s0);                                                 \
        if constexpr (cqp_ < 3) ILOAD(cqp_ + 1, 1, s1);                     \
    } else if constexpr (cqp_ < 3) {                                        \
        ILOAD(cqp_ + 1, 2, s0); ILOAD(cqp_ + 1, 3, s1);                     \
    }                                                                       \
    asm volatile("" ::: "memory");  /* keep loads issued early */           \
    { int roff[7];                                                          \
      _Pragma("unroll")                                                     \
      for (int nf = 0; nf < 7; ++nf) {                                      \
          int t = 6 * cqp_ + rp_ + yl[nf];                                  \
          roff[nf] = (t >= 12 ? t - 12 : t) << 12;                          \
      }                                                                     \
      STEP(PH, 0); STEP(PH, 1); STEP(PH, 2);                                \
    }                                                                       \
    if constexpr (rp_ == 0) {                                               \
        IWRITE(cqp_, 4, s0);                                                \
        if constexpr (cqp_ < 3) IWRITE(cqp_ + 1, 0, s1);                    \
    } else if constexpr (rp_ == 1) {                                        \
        IWRITE(cqp_, 5, s0);                                                \
        if constexpr (cqp_ < 3) IWRITE(cqp_ + 1, 1, s1);                    \
    } else if constexpr (cqp_ < 3) {                                        \
        IWRITE(cqp_ + 1, 2, s0); IWRITE(cqp_ + 1, 3, s1);                   \
    }                                                                       \
    asm volatile("s_waitcnt lgkmcnt(0)" ::: "memory");                      \
    asm volatile("s_barrier" ::: "memory");                                 \
} while (0)

    PHASE(0);  PHASE(1);  PHASE(2);  PHASE(3);
    PHASE(4);  PHASE(5);  PHASE(6);  PHASE(7);
    PHASE(8);  PHASE(9);  PHASE(10); PHASE(11);

#undef PHASE
#undef STEP
#undef IWRITE
#undef ILOAD
#undef LOAD_WS

    // epilogue: D col = l15 (pixel), row = lk*4 + j (ko)
    const int sp0 = rb * 56 + wpx;
#pragma unroll
    for (int m = 0; m < 4; ++m) {
        int kb = koh * 128 + wkol + m * 16 + lk * 4;
        f32x4 bs = *(const f32x4*)(bias + kb);
#pragma unroll
        for (int nf = 0; nf < 7; ++nf) {
            float* ob = out + ((size_t)(n * K_OUT + kb) * IMG) + sp0 + nf * 16 + l15;
#pragma unroll
            for (int j = 0; j < 4; ++j)
                ob[(size_t)j * IMG] = acc[m][nf][j] + bs[j];
        }
    }
}

// ---- fallback (only if ws too small): naive fp32 direct conv ----
__global__ void conv_naive(const float* __restrict__ inp,
                           const float* __restrict__ ker,
                           const float* __restrict__ bias,
                           float* __restrict__ out, int total) {
    int o = blockIdx.x * blockDim.x + threadIdx.x;
    if (o >= total) return;
    int x = o % HW, y = (o / HW) % HW, ko = (o / IMG) % K_OUT, n = o / (IMG * K_OUT);
    float acc = bias[ko];
    for (int c = 0; c < C_IN; ++c)
        for (int r = 0; r < 3; ++r) {
            int iy = y + r - 1; if ((unsigned)iy >= HW) continue;
            for (int s = 0; s < 3; ++s) {
                int ix = x + s - 1; if ((unsigned)ix >= HW) continue;
                acc += inp[((n * C_IN + c) * HW + iy) * HW + ix]
                     * ker[((ko * C_IN + c) * 3 + r) * 3 + s];
            }
        }
    out[o] = acc;
}

extern "C" void kernel_launch(void* const* d_in, const int* in_sizes, int n_in,
                              void* d_out, int out_size, void* d_ws, size_t ws_size,
                              hipStream_t stream) {
    const float* inp  = (const float*)d_in[0];
    const float* ker  = (const float*)d_in[1];
    const float* bias = (const float*)d_in[2];
    float* out = (float*)d_out;

    const size_t need = WT_WS_USHORT * 2;
    if (ws_size < need) {
        int total = NBATCH * K_OUT * IMG;
        conv_naive<<<(total + 255) / 256, 256, 0, stream>>>(inp, ker, bias, out, total);
        return;
    }

    unsigned short* wtb = (unsigned short*)d_ws;

    prep_weights<<<144, 256, 0, stream>>>(ker, wtb);
    conv_mfma<<<dim3(448, 2), 256, 0, stream>>>(inp, wtb, bias, out);
}